// Round 8
// baseline (450.425 us; speedup 1.0000x reference)
//
#include <hip/hip_runtime.h>
#include <math.h>

#define NROWS 32768
#define DDIM 256
#define KEMB 1024

#define OFF_COMMIT 8388608
#define OFF_EMBED  8388609
#define OFF_ENT    8388610
#define OFF_IDX    8388611

// ws float layout: [0..1023] avg_prob sums, [1024] H sum, [1025] sqdiff sum,
// [1026..2049] cnorm, [4096..266239] cb bf16 hi/lo fragment image (1 MB).
#define WS_IMG_F 4096

// prevent -ffp-contract=fast from fusing this mul into a following add
#define NOFUSE(x) asm volatile("" : "+v"(x))

typedef __attribute__((ext_vector_type(8))) short bf16x8;
typedef __attribute__((ext_vector_type(16))) float f32x16;
#define MFMA32(a, b, c) __builtin_amdgcn_mfma_f32_32x32x16_bf16((a), (b), (c), 0, 0, 0)

// round-to-nearest-even fp32 -> bf16 hi + bf16 lo split
__device__ inline void bf16split(float x, unsigned short& h, unsigned short& l) {
  unsigned u = __float_as_uint(x);
  unsigned r = u + 0x7FFFu + ((u >> 16) & 1u);
  h = (unsigned short)(r >> 16);
  float hf = __uint_as_float(r & 0xFFFF0000u);
  float lo = x - hf;  // exact (Sterbenz)
  unsigned ul = __float_as_uint(lo);
  unsigned rl = ul + 0x7FFFu + ((ul >> 16) & 1u);
  l = (unsigned short)(rl >> 16);
}

// ---- fused pre-pass ----
// blocks 0..63: cnorm = np.sum(cb**2, axis=1), numpy pairwise order bit-exact
// blocks 64..191: build cb bf16 fragment image (direct MFMA B-frag layout)
// frag f = ((kc*32 + ct)*2 + hl)*64 + lane holds cb[ct*32+l31][kc*16+lhi*8..+7]
__global__ __launch_bounds__(256) void vq_pre(const float* __restrict__ cb,
                                              float* __restrict__ ws) {
  const int tid = threadIdx.x;
  if (blockIdx.x < 64) {
    int t = blockIdx.x * 256 + tid;  // [0,16384)
    if (t < 1026) ws[t] = 0.0f;
    int row = t >> 4;  // 0..1023
    int l = t & 15;
    int h = l >> 3, j = l & 7;
    const float* xp = cb + (size_t)row * DDIM + h * 128 + j;
    float x = xp[0];
    float sq = x * x; NOFUSE(sq);
    float r = sq;
#pragma unroll
    for (int tt = 1; tt < 16; ++tt) {
      x = xp[8 * tt];
      sq = x * x; NOFUSE(sq);
      r = r + sq;
    }
    r = r + __shfl_xor(r, 1, 64);
    r = r + __shfl_xor(r, 2, 64);
    r = r + __shfl_xor(r, 4, 64);
    r = r + __shfl_xor(r, 8, 64);
    if (l == 0) ws[1026 + row] = r;
  } else {
    unsigned short* img = (unsigned short*)(ws + WS_IMG_F);
    int t = (blockIdx.x - 64) * 256 + tid;  // [0,32768)
    int kc = t >> 11;
    int ct = (t >> 6) & 31;
    int lane = t & 63;
    int l31 = lane & 31, lhi = lane >> 5;
    const float* src = cb + ((size_t)(ct * 32 + l31) << 8) + kc * 16 + lhi * 8;
    float4 v0 = *(const float4*)(src);
    float4 v1 = *(const float4*)(src + 4);
    bf16x8 hv, lv;
    unsigned short hh, ll;
    bf16split(v0.x, hh, ll); hv[0] = hh; lv[0] = ll;
    bf16split(v0.y, hh, ll); hv[1] = hh; lv[1] = ll;
    bf16split(v0.z, hh, ll); hv[2] = hh; lv[2] = ll;
    bf16split(v0.w, hh, ll); hv[3] = hh; lv[3] = ll;
    bf16split(v1.x, hh, ll); hv[4] = hh; lv[4] = ll;
    bf16split(v1.y, hh, ll); hv[5] = hh; lv[5] = ll;
    bf16split(v1.z, hh, ll); hv[6] = hh; lv[6] = ll;
    bf16split(v1.w, hh, ll); hv[7] = hh; lv[7] = ll;
    size_t f = ((size_t)(kc * 32 + ct) * 2) * 64 + lane;  // hl=0
    *(bf16x8*)(img + f * 8) = hv;
    *(bf16x8*)(img + (f + 64) * 8) = lv;                  // hl=1
  }
}

// ---- MFMA main v4: BM=32, 1024 threads (16 waves), 2 col-tiles/wave.
// acc[2]=32 AGPR + <=96 VGPR -> 4 waves/SIMD; 1-deep register prefetch of
// B-frags (global, L2-resident img) and A-frags (LDS). No barriers in K-loop.
// LDS: [0,16K) zh, [16K,32K) zl ; epilogue alias: pacc 4K, logits[16][1024]
// 64K at +4K, redH/redS at +68K.
__global__ __launch_bounds__(1024, 4) void vq_main4(const float* __restrict__ z,
                                                    const float* __restrict__ cb,
                                                    const unsigned short* __restrict__ img,
                                                    float* __restrict__ out,
                                                    float* __restrict__ ws) {
  __shared__ __align__(16) unsigned char smem[69888];
  unsigned short* zh_s = (unsigned short*)smem;
  unsigned short* zl_s = (unsigned short*)(smem + 16384);
  const int tid = threadIdx.x;
  const int w = tid >> 6;          // wave 0..15
  const int lane = tid & 63;
  const int l31 = lane & 31, lhi = lane >> 5;
  const int nbase = blockIdx.x * 32;
  const float* cnorm = ws + 1026;

  // stage z rows 0..31: fp32 -> bf16 hi/lo, XOR-swizzled 16B units
#pragma unroll
  for (int i = 0; i < 8; ++i) {
    int idx = tid + (i << 10);
    int row = idx >> 8, k = idx & 255;
    float x = z[((size_t)(nbase + row) << 8) + k];
    unsigned short hh, ll;
    bf16split(x, hh, ll);
    int uoff = (row << 8) | ((((k >> 3) ^ row) & 31) << 3) | (k & 7);
    zh_s[uoff] = hh; zl_s[uoff] = ll;
  }
  __syncthreads();

  f32x16 acc0, acc1;
#pragma unroll
  for (int e = 0; e < 16; ++e) { acc0[e] = 0.0f; acc1[e] = 0.0f; }

  const int ct0 = w * 2, ct1 = w * 2 + 1;
  const unsigned short* pw = img + lane * 8;
  // preload kc=0
  const unsigned short* p0 = pw + ct0 * 1024;
  const unsigned short* p1 = pw + ct1 * 1024;
  bf16x8 nbh0 = *(const bf16x8*)(p0);
  bf16x8 nbl0 = *(const bf16x8*)(p0 + 512);
  bf16x8 nbh1 = *(const bf16x8*)(p1);
  bf16x8 nbl1 = *(const bf16x8*)(p1 + 512);
  int au0 = (l31 << 8) | (((lhi ^ l31) & 31) << 3);
  bf16x8 nazh = *(const bf16x8*)(zh_s + au0);
  bf16x8 nazl = *(const bf16x8*)(zl_s + au0);

#pragma unroll 1
  for (int kc = 0; kc < 16; ++kc) {
    bf16x8 ch0 = nbh0, cl0 = nbl0, ch1 = nbh1, cl1 = nbl1;
    bf16x8 cah = nazh, cal = nazl;
    // issue next-kc loads (kc=15 wraps to 0: valid memory, results unused)
    const int kn = (kc + 1) & 15;
    const unsigned short* pk = pw + kn * 32768;
    const unsigned short* q0 = pk + ct0 * 1024;
    const unsigned short* q1 = pk + ct1 * 1024;
    nbh0 = *(const bf16x8*)(q0);
    nbl0 = *(const bf16x8*)(q0 + 512);
    nbh1 = *(const bf16x8*)(q1);
    nbl1 = *(const bf16x8*)(q1 + 512);
    const int aun = (l31 << 8) | (((((kn << 1) | lhi) ^ l31) & 31) << 3);
    nazh = *(const bf16x8*)(zh_s + aun);
    nazl = *(const bf16x8*)(zl_s + aun);
    // split-bf16 3-pass MFMA on current-kc fragments
    acc0 = MFMA32(cah, ch0, acc0);
    acc0 = MFMA32(cah, cl0, acc0);
    acc0 = MFMA32(cal, ch0, acc0);
    acc1 = MFMA32(cah, ch1, acc1);
    acc1 = MFMA32(cah, cl1, acc1);
    acc1 = MFMA32(cal, ch1, acc1);
  }

  // ---- epilogue: 2 groups of 16 rows, 64 lanes per row ----
  float* pacc = (float*)smem;                    // 1024 f
  float* logits = (float*)(smem + 4096);         // [16][1024]
  float* redH = (float*)(smem + 69632);          // 32 f
  float* redS = (float*)(smem + 69760);          // 32 f
  const float cn0 = cnorm[ct0 * 32 + l31];
  const float cn1 = cnorm[ct1 * 32 + l31];
  __syncthreads();  // all K-loop LDS reads complete before alias reuse
  pacc[tid] = 0.0f;
  const int erow = tid >> 6, ecl = tid & 63;
#pragma unroll
  for (int g = 0; g < 2; ++g) {
    __syncthreads();  // pacc-zero visible / prev-group logit reads done
#pragma unroll
    for (int q = 0; q < 8; ++q) {
      int reg = q + (g << 3);
      int r16 = (q & 3) | ((q >> 2) << 3) | (lhi << 2);
      logits[(r16 << 10) + ct0 * 32 + l31] = 200.0f * acc0[reg] - 100.0f * cn0;
      logits[(r16 << 10) + ct1 * 32 + l31] = 200.0f * acc1[reg] - 100.0f * cn1;
    }
    __syncthreads();
    const int grow = nbase + (g << 4) + erow;
    float v2[16];  // cols ecl + 64m, ascending
#pragma unroll
    for (int m = 0; m < 16; ++m) v2[m] = logits[(erow << 10) + ecl + (m << 6)];
    // top-2 argmax (== argmin distance), tie -> smaller index
    float m1 = -3.4e38f, m2v = -3.4e38f;
    int c1 = 0;
#pragma unroll
    for (int m = 0; m < 16; ++m) {
      float val = v2[m];
      if (val > m1) { m2v = m1; m1 = val; c1 = ecl + (m << 6); }
      else if (val > m2v) { m2v = val; }
    }
#pragma unroll
    for (int mk = 1; mk < 64; mk <<= 1) {
      float om1 = __shfl_xor(m1, mk, 64);
      int oc1 = __shfl_xor(c1, mk, 64);
      float om2 = __shfl_xor(m2v, mk, 64);
      if (om1 > m1 || (om1 == m1 && oc1 < c1)) { m2v = fmaxf(m1, om2); m1 = om1; c1 = oc1; }
      else { m2v = fmaxf(om1, m2v); }
    }
    const float rowmax = m1;
    const int bcol = c1;
    const bool danger = (m1 - m2v) < 0.25f;  // ~2500x MFMA-path error bound
    // softmax stats
    float S = 0.f, T = 0.f;
#pragma unroll
    for (int m = 0; m < 16; ++m) {
      float e = __expf(v2[m] - rowmax);
      S += e;
      T = fmaf(e, v2[m], T);
      v2[m] = e;
    }
#pragma unroll
    for (int mk = 1; mk < 64; mk <<= 1) {
      S += __shfl_xor(S, mk, 64);
      T += __shfl_xor(T, mk, 64);
    }
    const float invZ = 1.0f / S;
    const float H = rowmax + logf(S) - T * invZ;
#pragma unroll
    for (int m = 0; m < 16; ++m) atomicAdd(&pacc[ecl + (m << 6)], v2[m] * invZ);
    // quantized write (straight-through, exact ref op order) + sqdiff
    float sq = 0.f;
    {
      const float* zr = z + ((size_t)grow << 8) + (ecl << 2);
      const float* cr = cb + ((size_t)bcol << 8) + (ecl << 2);
      float* orow = out + ((size_t)grow << 8) + (ecl << 2);
      float4 zv = *(const float4*)(zr);
      float4 cv = *(const float4*)(cr);
      float4 qv;
      qv.x = zv.x + (cv.x - zv.x);
      qv.y = zv.y + (cv.y - zv.y);
      qv.z = zv.z + (cv.z - zv.z);
      qv.w = zv.w + (cv.w - zv.w);
      *(float4*)(orow) = qv;
      float dx = cv.x - zv.x; sq = fmaf(dx, dx, sq);
      dx = cv.y - zv.y; sq = fmaf(dx, dx, sq);
      dx = cv.z - zv.z; sq = fmaf(dx, dx, sq);
      dx = cv.w - zv.w; sq = fmaf(dx, dx, sq);
    }
#pragma unroll
    for (int mk = 1; mk < 64; mk <<= 1) sq += __shfl_xor(sq, mk, 64);
    if (ecl == 0) {
      redH[(g << 4) + erow] = H;
      redS[(g << 4) + erow] = sq;
      out[OFF_IDX + grow] = danger ? -(float)(bcol + 1) : (float)bcol;
    }
  }
  __syncthreads();
  atomicAdd(&ws[tid], pacc[tid]);
  if (tid == 0) {
    float hs = 0.f, ss = 0.f;
#pragma unroll
    for (int i = 0; i < 32; ++i) { hs += redH[i]; ss += redS[i]; }
    atomicAdd(&ws[1024], hs);
    atomicAdd(&ws[1025], ss);
  }
}

// ---- fused tail ----
// blocks 0..255: ballot-scan re-resolve of contested rows (bit-level numpy
// emulation; each wave owns 32 rows). block 256: final loss reduction.
__global__ __launch_bounds__(256) void vq_fixfinal(const float* __restrict__ z,
                                                   const float* __restrict__ cb,
                                                   float* __restrict__ out,
                                                   const float* __restrict__ ws) {
  if (blockIdx.x == 256) {
    __shared__ float red[256];
    int t = threadIdx.x;
    float s = 0.f;
#pragma unroll
    for (int i = 0; i < 4; ++i) {
      float a = ws[t + i * 256] * (1.0f / 32768.0f);
      s += a * logf(a + 1e-5f);
    }
    red[t] = s;
    __syncthreads();
    for (int st = 128; st > 0; st >>= 1) {
      if (t < st) red[t] += red[t + st];
      __syncthreads();
    }
    if (t == 0) {
      float avg_entropy = -red[0];
      float sample_entropy = ws[1024] * (1.0f / 32768.0f);
      float m = ws[1025] * (1.0f / 8388608.0f);
      out[OFF_COMMIT] = 0.25f * m;
      out[OFF_EMBED] = m;
      out[OFF_ENT] = 0.1f * (sample_entropy - avg_entropy);
    }
    return;
  }

  const int lane = threadIdx.x & 63;
  const int gwave = (int)((blockIdx.x * 256 + threadIdx.x) >> 6);  // 0..1023
  const int rbase = gwave * 32;
  const float* cnorm = ws + 1026;

  float iv = (lane < 32) ? out[OFF_IDX + rbase + lane] : 0.0f;
  unsigned long long mask = __ballot(iv < 0.0f);
  while (mask) {
    int bit = __ffsll((long long)mask) - 1;
    mask &= mask - 1;
    int row = rbase + bit;
    float ivr = __shfl(iv, bit, 64);
    int kold = (int)(-ivr) - 1;
    const float* zr = z + (size_t)row * DDIM;

    // znorm, numpy pairwise (lanes 0..15 carry the 16 accumulators)
    float r;
    {
      int h = (lane & 15) >> 3, j = lane & 7;
      const float* xp = zr + h * 128 + j;
      float x = xp[0];
      float sq = x * x; NOFUSE(sq);
      r = sq;
#pragma unroll
      for (int tt = 1; tt < 16; ++tt) {
        x = xp[8 * tt];
        sq = x * x; NOFUSE(sq);
        r = r + sq;
      }
    }
    r = r + __shfl_xor(r, 1, 64);
    r = r + __shfl_xor(r, 2, 64);
    r = r + __shfl_xor(r, 4, 64);
    r = r + __shfl_xor(r, 8, 64);
    const float znorm = __shfl(r, 0, 64);

    // emulated distances: dot = sequential ascending-k fp32 FMA chain
    float bd = 3.4e38f;
    int bk = 0;
#pragma unroll 1
    for (int t = 0; t < 16; ++t) {
      int k = lane + t * 64;
      const float* cr = cb + (size_t)k * DDIM;
      float acc = 0.0f;
#pragma unroll 8
      for (int d = 0; d < 256; ++d) acc = fmaf(zr[d], cr[d], acc);
      float dist = (znorm - 2.0f * acc) + cnorm[k];
      if (dist < bd) { bd = dist; bk = k; }
    }
#pragma unroll
    for (int m = 1; m < 64; m <<= 1) {
      float od = __shfl_xor(bd, m, 64);
      int ok = __shfl_xor(bk, m, 64);
      if (od < bd || (od == bd && ok < bk)) { bd = od; bk = ok; }
    }

    if (bk != kold) {
      const float* cr = cb + (size_t)bk * DDIM;
#pragma unroll
      for (int i = 0; i < 4; ++i) {
        int d0 = lane + i * 64;
        float zd = zr[d0], cd = cr[d0];
        out[(size_t)row * DDIM + d0] = zd + (cd - zd);
      }
    }
    if (lane == 0) out[OFF_IDX + row] = (float)bk;
  }
}

extern "C" void kernel_launch(void* const* d_in, const int* in_sizes, int n_in,
                              void* d_out, int out_size, void* d_ws, size_t ws_size,
                              hipStream_t stream) {
  const float* z = (const float*)d_in[0];
  const float* cb = (const float*)d_in[1];
  float* out = (float*)d_out;
  float* ws = (float*)d_ws;

  vq_pre<<<192, 256, 0, stream>>>(cb, ws);
  vq_main4<<<NROWS / 32, 1024, 0, stream>>>(
      z, cb, (const unsigned short*)(ws + WS_IMG_F), out, ws);
  vq_fixfinal<<<257, 256, 0, stream>>>(z, cb, out, ws);
}

// Round 10
// 441.160 us; speedup vs baseline: 1.0210x; 1.0210x over previous
//
#include <hip/hip_runtime.h>
#include <math.h>

#define NROWS 32768
#define DDIM 256
#define KEMB 1024

#define OFF_COMMIT 8388608
#define OFF_EMBED  8388609
#define OFF_ENT    8388610
#define OFF_IDX    8388611

// ws float layout: [0..1023] avg_prob sums, [1024] H sum, [1025] sqdiff sum,
// [1026..2049] cnorm, [4096..266239] cb bf16 hi/lo fragment image (1 MB).
#define WS_IMG_F 4096

// prevent -ffp-contract=fast from fusing this mul into a following add
#define NOFUSE(x) asm volatile("" : "+v"(x))

typedef __attribute__((ext_vector_type(8))) short bf16x8;
typedef __attribute__((ext_vector_type(16))) float f32x16;
#define MFMA32(a, b, c) __builtin_amdgcn_mfma_f32_32x32x16_bf16((a), (b), (c), 0, 0, 0)

// round-to-nearest-even fp32 -> bf16 hi + bf16 lo split
__device__ inline void bf16split(float x, unsigned short& h, unsigned short& l) {
  unsigned u = __float_as_uint(x);
  unsigned r = u + 0x7FFFu + ((u >> 16) & 1u);
  h = (unsigned short)(r >> 16);
  float hf = __uint_as_float(r & 0xFFFF0000u);
  float lo = x - hf;  // exact (Sterbenz)
  unsigned ul = __float_as_uint(lo);
  unsigned rl = ul + 0x7FFFu + ((ul >> 16) & 1u);
  l = (unsigned short)(rl >> 16);
}

// ---- fused pre-pass ----
// blocks 0..63: cnorm = np.sum(cb**2, axis=1), numpy pairwise order bit-exact
// blocks 64..191: build cb bf16 fragment image (direct MFMA B-frag layout)
// frag f = ((kc*32 + ct)*2 + hl)*64 + lane holds cb[ct*32+l31][kc*16+lhi*8..+7]
__global__ __launch_bounds__(256) void vq_pre(const float* __restrict__ cb,
                                              float* __restrict__ ws) {
  const int tid = threadIdx.x;
  if (blockIdx.x < 64) {
    int t = blockIdx.x * 256 + tid;  // [0,16384)
    if (t < 1026) ws[t] = 0.0f;
    int row = t >> 4;  // 0..1023
    int l = t & 15;
    int h = l >> 3, j = l & 7;
    const float* xp = cb + (size_t)row * DDIM + h * 128 + j;
    float x = xp[0];
    float sq = x * x; NOFUSE(sq);
    float r = sq;
#pragma unroll
    for (int tt = 1; tt < 16; ++tt) {
      x = xp[8 * tt];
      sq = x * x; NOFUSE(sq);
      r = r + sq;
    }
    r = r + __shfl_xor(r, 1, 64);
    r = r + __shfl_xor(r, 2, 64);
    r = r + __shfl_xor(r, 4, 64);
    r = r + __shfl_xor(r, 8, 64);
    if (l == 0) ws[1026 + row] = r;
  } else {
    unsigned short* img = (unsigned short*)(ws + WS_IMG_F);
    int t = (blockIdx.x - 64) * 256 + tid;  // [0,32768)
    int kc = t >> 11;
    int ct = (t >> 6) & 31;
    int lane = t & 63;
    int l31 = lane & 31, lhi = lane >> 5;
    const float* src = cb + ((size_t)(ct * 32 + l31) << 8) + kc * 16 + lhi * 8;
    float4 v0 = *(const float4*)(src);
    float4 v1 = *(const float4*)(src + 4);
    bf16x8 hv, lv;
    unsigned short hh, ll;
    bf16split(v0.x, hh, ll); hv[0] = hh; lv[0] = ll;
    bf16split(v0.y, hh, ll); hv[1] = hh; lv[1] = ll;
    bf16split(v0.z, hh, ll); hv[2] = hh; lv[2] = ll;
    bf16split(v0.w, hh, ll); hv[3] = hh; lv[3] = ll;
    bf16split(v1.x, hh, ll); hv[4] = hh; lv[4] = ll;
    bf16split(v1.y, hh, ll); hv[5] = hh; lv[5] = ll;
    bf16split(v1.z, hh, ll); hv[6] = hh; lv[6] = ll;
    bf16split(v1.w, hh, ll); hv[7] = hh; lv[7] = ll;
    size_t f = ((size_t)(kc * 32 + ct) * 2) * 64 + lane;  // hl=0
    *(bf16x8*)(img + f * 8) = hv;
    *(bf16x8*)(img + (f + 64) * 8) = lv;                  // hl=1
  }
}

// ---- MFMA main v5: PERSISTENT blocks. grid=256 (1/CU), each block owns
// 4 tiles of 32 rows. pacc/H/sq accumulate locally across tiles; global
// atomics ONCE per block (contenders per ws address: 1024 -> 256).
// 1024 threads (16 waves), 2 col-tiles/wave, acc0/acc1 interleaved MFMA,
// 1-deep register prefetch. LDS 100.2KB: pacc@0 (4K), zh@4K (16K),
// zl@20K (16K), logits@36K (64K), redH/redS@100K.
__global__ __launch_bounds__(1024, 4) void vq_main5(const float* __restrict__ z,
                                                    const float* __restrict__ cb,
                                                    const unsigned short* __restrict__ img,
                                                    float* __restrict__ out,
                                                    float* __restrict__ ws) {
  __shared__ __align__(16) unsigned char smem[102656];
  float* pacc = (float*)smem;                          // 1024 f, persistent
  unsigned short* zh_s = (unsigned short*)(smem + 4096);
  unsigned short* zl_s = (unsigned short*)(smem + 20480);
  float* logits = (float*)(smem + 36864);              // [16][1024]
  float* redH = (float*)(smem + 102400);               // 16 f
  float* redS = (float*)(smem + 102464);               // 16 f

  const int tid = threadIdx.x;
  const int w = tid >> 6;          // wave 0..15
  const int lane = tid & 63;
  const int l31 = lane & 31, lhi = lane >> 5;
  const float* cnorm = ws + 1026;
  const int ct0 = w * 2, ct1 = w * 2 + 1;
  const unsigned short* pw = img + lane * 8;
  const float cn0 = cnorm[ct0 * 32 + l31];
  const float cn1 = cnorm[ct1 * 32 + l31];
  const int erow = tid >> 6, ecl = tid & 63;

  pacc[tid] = 0.0f;   // ordered vs first reads by the post-staging barrier
  float hacc = 0.0f, sqacc = 0.0f;

#pragma unroll 1
  for (int t = 0; t < 4; ++t) {
    const int nbase = (blockIdx.x * 4 + t) * 32;

    // stage z rows 0..31: fp32 -> bf16 hi/lo, XOR-swizzled 16B units
#pragma unroll
    for (int i = 0; i < 8; ++i) {
      int idx = tid + (i << 10);
      int row = idx >> 8, k = idx & 255;
      float x = z[((size_t)(nbase + row) << 8) + k];
      unsigned short hh, ll;
      bf16split(x, hh, ll);
      int uoff = (row << 8) | ((((k >> 3) ^ row) & 31) << 3) | (k & 7);
      zh_s[uoff] = hh; zl_s[uoff] = ll;
    }
    __syncthreads();  // staging visible; also orders prev-tile epilogue reads

    f32x16 acc0, acc1;
#pragma unroll
    for (int e = 0; e < 16; ++e) { acc0[e] = 0.0f; acc1[e] = 0.0f; }

    // preload kc=0
    const unsigned short* p0 = pw + ct0 * 1024;
    const unsigned short* p1 = pw + ct1 * 1024;
    bf16x8 nbh0 = *(const bf16x8*)(p0);
    bf16x8 nbl0 = *(const bf16x8*)(p0 + 512);
    bf16x8 nbh1 = *(const bf16x8*)(p1);
    bf16x8 nbl1 = *(const bf16x8*)(p1 + 512);
    int au0 = (l31 << 8) | (((lhi ^ l31) & 31) << 3);
    bf16x8 nazh = *(const bf16x8*)(zh_s + au0);
    bf16x8 nazl = *(const bf16x8*)(zl_s + au0);

#pragma unroll 1
    for (int kc = 0; kc < 16; ++kc) {
      bf16x8 ch0 = nbh0, cl0 = nbl0, ch1 = nbh1, cl1 = nbl1;
      bf16x8 cah = nazh, cal = nazl;
      // issue next-kc loads (kc=15 wraps to 0: valid memory, results unused)
      const int kn = (kc + 1) & 15;
      const unsigned short* pk = pw + kn * 32768;
      const unsigned short* q0 = pk + ct0 * 1024;
      const unsigned short* q1 = pk + ct1 * 1024;
      nbh0 = *(const bf16x8*)(q0);
      nbl0 = *(const bf16x8*)(q0 + 512);
      nbh1 = *(const bf16x8*)(q1);
      nbl1 = *(const bf16x8*)(q1 + 512);
      const int aun = (l31 << 8) | (((((kn << 1) | lhi) ^ l31) & 31) << 3);
      nazh = *(const bf16x8*)(zh_s + aun);
      nazl = *(const bf16x8*)(zl_s + aun);
      // split-bf16 3-pass MFMA, acc0/acc1 interleaved (dep distance 2)
      acc0 = MFMA32(cah, ch0, acc0);
      acc1 = MFMA32(cah, ch1, acc1);
      acc0 = MFMA32(cah, cl0, acc0);
      acc1 = MFMA32(cah, cl1, acc1);
      acc0 = MFMA32(cal, ch0, acc0);
      acc1 = MFMA32(cal, ch1, acc1);
    }

    // ---- per-tile epilogue: 2 groups of 16 rows, 64 lanes per row ----
#pragma unroll
    for (int g = 0; g < 2; ++g) {
      __syncthreads();  // prev-group logits reads done before rewrite
#pragma unroll
      for (int q = 0; q < 8; ++q) {
        int reg = q + (g << 3);
        int r16 = (q & 3) | ((q >> 2) << 3) | (lhi << 2);
        logits[(r16 << 10) + ct0 * 32 + l31] = 200.0f * acc0[reg] - 100.0f * cn0;
        logits[(r16 << 10) + ct1 * 32 + l31] = 200.0f * acc1[reg] - 100.0f * cn1;
      }
      __syncthreads();
      const int grow = nbase + (g << 4) + erow;
      float v2[16];  // cols ecl + 64m, ascending
#pragma unroll
      for (int m = 0; m < 16; ++m) v2[m] = logits[(erow << 10) + ecl + (m << 6)];
      // top-2 argmax (== argmin distance), tie -> smaller index
      float m1 = -3.4e38f, m2v = -3.4e38f;
      int c1 = 0;
#pragma unroll
      for (int m = 0; m < 16; ++m) {
        float val = v2[m];
        if (val > m1) { m2v = m1; m1 = val; c1 = ecl + (m << 6); }
        else if (val > m2v) { m2v = val; }
      }
#pragma unroll
      for (int mk = 1; mk < 64; mk <<= 1) {
        float om1 = __shfl_xor(m1, mk, 64);
        int oc1 = __shfl_xor(c1, mk, 64);
        float om2 = __shfl_xor(m2v, mk, 64);
        if (om1 > m1 || (om1 == m1 && oc1 < c1)) { m2v = fmaxf(m1, om2); m1 = om1; c1 = oc1; }
        else { m2v = fmaxf(om1, m2v); }
      }
      const float rowmax = m1;
      const int bcol = c1;
      const bool danger = (m1 - m2v) < 0.25f;  // ~2500x MFMA-path error bound
      // softmax stats
      float S = 0.f, T = 0.f;
#pragma unroll
      for (int m = 0; m < 16; ++m) {
        float e = __expf(v2[m] - rowmax);
        S += e;
        T = fmaf(e, v2[m], T);
        v2[m] = e;
      }
#pragma unroll
      for (int mk = 1; mk < 64; mk <<= 1) {
        S += __shfl_xor(S, mk, 64);
        T += __shfl_xor(T, mk, 64);
      }
      const float invZ = 1.0f / S;
      const float H = rowmax + logf(S) - T * invZ;
#pragma unroll
      for (int m = 0; m < 16; ++m) atomicAdd(&pacc[ecl + (m << 6)], v2[m] * invZ);
      // quantized write (straight-through, exact ref op order) + sqdiff
      float sq = 0.f;
      {
        const float* zr = z + ((size_t)grow << 8) + (ecl << 2);
        const float* cr = cb + ((size_t)bcol << 8) + (ecl << 2);
        float* orow = out + ((size_t)grow << 8) + (ecl << 2);
        float4 zv = *(const float4*)(zr);
        float4 cv = *(const float4*)(cr);
        float4 qv;
        qv.x = zv.x + (cv.x - zv.x);
        qv.y = zv.y + (cv.y - zv.y);
        qv.z = zv.z + (cv.z - zv.z);
        qv.w = zv.w + (cv.w - zv.w);
        *(float4*)(orow) = qv;
        float dx = cv.x - zv.x; sq = fmaf(dx, dx, sq);
        dx = cv.y - zv.y; sq = fmaf(dx, dx, sq);
        dx = cv.z - zv.z; sq = fmaf(dx, dx, sq);
        dx = cv.w - zv.w; sq = fmaf(dx, dx, sq);
      }
#pragma unroll
      for (int mk = 1; mk < 64; mk <<= 1) sq += __shfl_xor(sq, mk, 64);
      if (ecl == 0) {
        hacc += H;
        sqacc += sq;
        out[OFF_IDX + grow] = danger ? -(float)(bcol + 1) : (float)bcol;
      }
    }
  }

  // ---- ONE set of global atomics per block ----
  if (ecl == 0) { redH[erow] = hacc; redS[erow] = sqacc; }
  __syncthreads();
  atomicAdd(&ws[tid], pacc[tid]);
  if (tid == 0) {
    float hs = 0.f, ss = 0.f;
#pragma unroll
    for (int i = 0; i < 16; ++i) { hs += redH[i]; ss += redS[i]; }
    atomicAdd(&ws[1024], hs);
    atomicAdd(&ws[1025], ss);
  }
}

// ---- fused tail ----
// blocks 0..255: ballot-scan re-resolve of contested rows (bit-level numpy
// emulation; each wave owns 32 rows). block 256: final loss reduction.
__global__ __launch_bounds__(256) void vq_fixfinal(const float* __restrict__ z,
                                                   const float* __restrict__ cb,
                                                   float* __restrict__ out,
                                                   const float* __restrict__ ws) {
  if (blockIdx.x == 256) {
    __shared__ float red[256];
    int t = threadIdx.x;
    float s = 0.f;
#pragma unroll
    for (int i = 0; i < 4; ++i) {
      float a = ws[t + i * 256] * (1.0f / 32768.0f);
      s += a * logf(a + 1e-5f);
    }
    red[t] = s;
    __syncthreads();
    for (int st = 128; st > 0; st >>= 1) {
      if (t < st) red[t] += red[t + st];
      __syncthreads();
    }
    if (t == 0) {
      float avg_entropy = -red[0];
      float sample_entropy = ws[1024] * (1.0f / 32768.0f);
      float m = ws[1025] * (1.0f / 8388608.0f);
      out[OFF_COMMIT] = 0.25f * m;
      out[OFF_EMBED] = m;
      out[OFF_ENT] = 0.1f * (sample_entropy - avg_entropy);
    }
    return;
  }

  const int lane = threadIdx.x & 63;
  const int gwave = (int)((blockIdx.x * 256 + threadIdx.x) >> 6);  // 0..1023
  const int rbase = gwave * 32;
  const float* cnorm = ws + 1026;

  float iv = (lane < 32) ? out[OFF_IDX + rbase + lane] : 0.0f;
  unsigned long long mask = __ballot(iv < 0.0f);
  while (mask) {
    int bit = __ffsll((long long)mask) - 1;
    mask &= mask - 1;
    int row = rbase + bit;
    float ivr = __shfl(iv, bit, 64);
    int kold = (int)(-ivr) - 1;
    const float* zr = z + (size_t)row * DDIM;

    // znorm, numpy pairwise (lanes 0..15 carry the 16 accumulators)
    float r;
    {
      int h = (lane & 15) >> 3, j = lane & 7;
      const float* xp = zr + h * 128 + j;
      float x = xp[0];
      float sq = x * x; NOFUSE(sq);
      r = sq;
#pragma unroll
      for (int tt = 1; tt < 16; ++tt) {
        x = xp[8 * tt];
        sq = x * x; NOFUSE(sq);
        r = r + sq;
      }
    }
    r = r + __shfl_xor(r, 1, 64);
    r = r + __shfl_xor(r, 2, 64);
    r = r + __shfl_xor(r, 4, 64);
    r = r + __shfl_xor(r, 8, 64);
    const float znorm = __shfl(r, 0, 64);

    // emulated distances: dot = sequential ascending-k fp32 FMA chain
    float bd = 3.4e38f;
    int bk = 0;
#pragma unroll 1
    for (int t = 0; t < 16; ++t) {
      int k = lane + t * 64;
      const float* cr = cb + (size_t)k * DDIM;
      float acc = 0.0f;
#pragma unroll 8
      for (int d = 0; d < 256; ++d) acc = fmaf(zr[d], cr[d], acc);
      float dist = (znorm - 2.0f * acc) + cnorm[k];
      if (dist < bd) { bd = dist; bk = k; }
    }
#pragma unroll
    for (int m = 1; m < 64; m <<= 1) {
      float od = __shfl_xor(bd, m, 64);
      int ok = __shfl_xor(bk, m, 64);
      if (od < bd || (od == bd && ok < bk)) { bd = od; bk = ok; }
    }

    if (bk != kold) {
      const float* cr = cb + (size_t)bk * DDIM;
#pragma unroll
      for (int i = 0; i < 4; ++i) {
        int d0 = lane + i * 64;
        float zd = zr[d0], cd = cr[d0];
        out[(size_t)row * DDIM + d0] = zd + (cd - zd);
      }
    }
    if (lane == 0) out[OFF_IDX + row] = (float)bk;
  }
}

extern "C" void kernel_launch(void* const* d_in, const int* in_sizes, int n_in,
                              void* d_out, int out_size, void* d_ws, size_t ws_size,
                              hipStream_t stream) {
  const float* z = (const float*)d_in[0];
  const float* cb = (const float*)d_in[1];
  float* out = (float*)d_out;
  float* ws = (float*)d_ws;

  vq_pre<<<192, 256, 0, stream>>>(cb, ws);
  vq_main5<<<256, 1024, 0, stream>>>(
      z, cb, (const unsigned short*)(ws + WS_IMG_F), out, ws);
  vq_fixfinal<<<257, 256, 0, stream>>>(z, cb, out, ws);
}